// Round 11
// baseline (474.906 us; speedup 1.0000x reference)
//
#include <hip/hip_runtime.h>
#include <hip/hip_bf16.h>
#include <math.h>

#define BNROWS (4096*32)   // 131072
#define RB     64          // rows per MLP block = 2 states
#define LN32   3.4657359027997265f

typedef __attribute__((ext_vector_type(8))) short bf16x8;
typedef __attribute__((ext_vector_type(4))) float f32x4;

static __device__ __forceinline__ ushort f2bf(float x) {
    union { __hip_bfloat16 h; ushort u; } cv;
    cv.h = __float2bfloat16(x);
    return cv.u;
}

// ---------------------------------------------------------------------------
// Weight pack (fragment order for lane-contiguous 16B loads).
__global__ void prep_pack(const float* __restrict__ w1,
                          const float* __restrict__ w2,
                          ushort* __restrict__ pB1, ushort* __restrict__ pB2,
                          ushort* __restrict__ pB3, ushort* __restrict__ pB4) {
    int g = blockIdx.x * 256 + threadIdx.x;   // 19968 total
    ushort out[8];
    ushort* dst;
    if (g < 3072) {
        int lane = g & 63, gc = g >> 6;
        int t = gc / 3, c = gc % 3;
        int m = lane & 15, q = lane >> 4, n = t * 16 + m;
        #pragma unroll
        for (int j = 0; j < 8; ++j) {
            int k = c * 32 + q * 8 + j;
            out[j] = f2bf((k < 80) ? w1[k * 256 + n] : 0.f);
        }
        dst = &pB1[g * 8];
    } else if (g < 11264) {
        int gg = g - 3072;
        int lane = gg & 63, gc = gg >> 6;
        int t = gc >> 3, c = gc & 7;
        int m = lane & 15, q = lane >> 4, n = t * 16 + m;
        #pragma unroll
        for (int j = 0; j < 8; ++j)
            out[j] = f2bf(w2[(c * 32 + q * 8 + j) * 256 + n]);
        dst = &pB2[gg * 8];
    } else if (g < 19456) {
        int gg = g - 11264;
        int lane = gg & 63, gc = gg >> 6;
        int t = gc >> 3, c = gc & 7;
        int m = lane & 15, q = lane >> 4;
        #pragma unroll
        for (int j = 0; j < 8; ++j)
            out[j] = f2bf(w2[(t * 16 + m) * 256 + c * 32 + q * 8 + j]);
        dst = &pB3[gg * 8];
    } else if (g < 19968) {
        int gg = g - 19456;
        int lane = gg & 63, c = gg >> 6;
        int m = lane & 15, q = lane >> 4;
        #pragma unroll
        for (int j = 0; j < 8; ++j)
            out[j] = f2bf(w1[(64 + m) * 256 + c * 32 + q * 8 + j]);
        dst = &pB4[gg * 8];
    } else return;
    *(uint4*)dst = *(uint4*)out;
}

// ---------------------------------------------------------------------------
// Fused STEP kernel (round 11): mlp fwd+VJP (round-6 proven structure) with
// the SVGD of the block's own 2 states fused as a TAIL. Rationale: svgd as a
// standalone dispatch is latency-bound at 4 waves/SIMD with nothing to hide
// behind; as a tail, its stalls overlap other blocks' dense mlp waves on the
// same CU. Score never touches global memory (phase E -> LDS overlay).
// LDS overlays keep the footprint at 52224 B (3 blocks/CU):
//   - S[2][32*20] + X[2][32*20] overlay B1s (dead after phase B barrier),
//   - KM[2][1024] overlays B0 (dead after phase E / barrier 7).
// Tail is register-lean (d0-outer dist, no Xj/Sj reg caches) so kernel VGPR
// stays near the mlp's 60 (revert signal: VGPR > 100). Tail FLOP order is
// identical to svgd6 -> bit-identical outputs.
__global__ __launch_bounds__(512) void fused_step(
    const float* __restrict__ obs,      // [BN,64] f32
    const float* __restrict__ a_in,     // [BN,16]
    const float* __restrict__ b1,       // [256]
    const float* __restrict__ b2,       // [256]
    const float* __restrict__ w3,       // [256]
    const float* __restrict__ b3,       // [1]
    const ushort* __restrict__ pB1, const ushort* __restrict__ pB2,
    const ushort* __restrict__ pB3, const ushort* __restrict__ pB4,
    const float* __restrict__ logp_in,  // [BN] (ignored if first)
    float* __restrict__ logp_out,       // [BN]
    float* __restrict__ a_out,          // [BN,16]
    float* __restrict__ qout,           // [BN] (written if wantq)
    int first, int wantq)
{
    __shared__ __align__(16) ushort B0[RB * 264];   // h1 -> dz2 -> dz1 -> KM
    __shared__ __align__(16) ushort B1s[RB * 104];  // h0 -> X/S overlay
    __shared__ float qpart[8][RB];
    __shared__ float bias1[256], bias2[256], w3s[256];

    float* OV = (float*)B1s;          // tail overlay: X[2][640] | S[2][640]
    float* KMOV = (float*)B0;         // tail overlay: KM[2][1024]

    const int tid  = threadIdx.x;
    const int row0 = blockIdx.x * RB;

    // ---- Phase A: stage h0 = [obs(f32->bf16) | a->bf16 | 0pad] at stride 104
    {
        int r = tid >> 3, ch = tid & 7;                    // 512 units exactly
        const float* op = &obs[(size_t)(row0 + r) * 64 + ch * 8];
        float4 v0 = *(const float4*)op;
        float4 v1 = *(const float4*)(op + 4);
        ushort o[8];
        o[0] = f2bf(v0.x); o[1] = f2bf(v0.y); o[2] = f2bf(v0.z); o[3] = f2bf(v0.w);
        o[4] = f2bf(v1.x); o[5] = f2bf(v1.y); o[6] = f2bf(v1.z); o[7] = f2bf(v1.w);
        *(uint4*)&B1s[r * 104 + ch * 8] = *(uint4*)o;
    }
    if (tid < 256) {
        int r = tid >> 2, d0 = (tid & 3) * 4;
        float4 av = *(const float4*)&a_in[(size_t)(row0 + r) * 16 + d0];
        ushort4 pv;
        pv.x = f2bf(av.x); pv.y = f2bf(av.y); pv.z = f2bf(av.z); pv.w = f2bf(av.w);
        *(ushort4*)&B1s[r * 104 + 64 + d0] = pv;
        ushort4 zv; zv.x = zv.y = zv.z = zv.w = 0;
        *(ushort4*)&B1s[r * 104 + 80 + d0] = zv;
        bias1[tid] = b1[tid]; bias2[tid] = b2[tid]; w3s[tid] = w3[tid];
    }
    __syncthreads();                                       // (1)

    const int lane = tid & 63;
    const int w    = tid >> 6;        // wave 0..7 -> col-tiles {2w, 2w+1}
    const int m    = lane & 15;
    const int q    = lane >> 4;
    const int qk   = q * 8;

    f32x4 acc[4][2];                  // [row-tile][col-tile-in-wave]
    unsigned relumask = 0u;           // 32 bits: rt*8 + tc*4 + i

    // ---- Phase B: z1 = h0 @ w1 (+b1) ; relu -> B0 ; mask -> regs
    #pragma unroll
    for (int tc = 0; tc < 2; ++tc)
        #pragma unroll
        for (int rt = 0; rt < 4; ++rt) acc[rt][tc] = (f32x4){0.f, 0.f, 0.f, 0.f};
    for (int c = 0; c < 3; ++c) {
        bf16x8 af[4];
        #pragma unroll
        for (int rt = 0; rt < 4; ++rt)
            af[rt] = *(const bf16x8*)&B1s[(rt * 16 + m) * 104 + c * 32 + qk];
        #pragma unroll
        for (int tc = 0; tc < 2; ++tc) {
            bf16x8 wfr = *(const bf16x8*)&pB1[(((w * 2 + tc) * 3 + c) * 64 + lane) * 8];
            #pragma unroll
            for (int rt = 0; rt < 4; ++rt)
                acc[rt][tc] = __builtin_amdgcn_mfma_f32_16x16x32_bf16(wfr, af[rt], acc[rt][tc], 0, 0, 0);
        }
    }
    #pragma unroll
    for (int tc = 0; tc < 2; ++tc) {
        const float4 bv = *(const float4*)&bias1[(w * 2 + tc) * 16 + q * 4];
        const float bva[4] = {bv.x, bv.y, bv.z, bv.w};
        #pragma unroll
        for (int rt = 0; rt < 4; ++rt) {
            ushort4 pk;
            float z0 = acc[rt][tc][0] + bva[0];
            float z1 = acc[rt][tc][1] + bva[1];
            float z2 = acc[rt][tc][2] + bva[2];
            float z3 = acc[rt][tc][3] + bva[3];
            if (z0 > 0.f) relumask |= 1u << (rt * 8 + tc * 4 + 0);
            if (z1 > 0.f) relumask |= 1u << (rt * 8 + tc * 4 + 1);
            if (z2 > 0.f) relumask |= 1u << (rt * 8 + tc * 4 + 2);
            if (z3 > 0.f) relumask |= 1u << (rt * 8 + tc * 4 + 3);
            pk.x = f2bf(fmaxf(z0, 0.f)); pk.y = f2bf(fmaxf(z1, 0.f));
            pk.z = f2bf(fmaxf(z2, 0.f)); pk.w = f2bf(fmaxf(z3, 0.f));
            *(ushort4*)&B0[(rt * 16 + m) * 264 + (w * 2 + tc) * 16 + q * 4] = pk;
        }
    }
    __syncthreads();                                       // (2) B1s dead after here

    // ---- Phase C: z2 = h1 @ w2 (+b2) ; q partials (wantq) ; dz2 -> B0
    #pragma unroll
    for (int tc = 0; tc < 2; ++tc)
        #pragma unroll
        for (int rt = 0; rt < 4; ++rt) acc[rt][tc] = (f32x4){0.f, 0.f, 0.f, 0.f};
    for (int c = 0; c < 8; ++c) {
        bf16x8 af[4];
        #pragma unroll
        for (int rt = 0; rt < 4; ++rt)
            af[rt] = *(const bf16x8*)&B0[(rt * 16 + m) * 264 + c * 32 + qk];
        #pragma unroll
        for (int tc = 0; tc < 2; ++tc) {
            bf16x8 wfr = *(const bf16x8*)&pB2[(((w * 2 + tc) * 8 + c) * 64 + lane) * 8];
            #pragma unroll
            for (int rt = 0; rt < 4; ++rt)
                acc[rt][tc] = __builtin_amdgcn_mfma_f32_16x16x32_bf16(wfr, af[rt], acc[rt][tc], 0, 0, 0);
        }
    }
    __syncthreads();                                       // (3)
    {
        float qp[4] = {0.f, 0.f, 0.f, 0.f};
        #pragma unroll
        for (int tc = 0; tc < 2; ++tc) {
            const float4 bv = *(const float4*)&bias2[(w * 2 + tc) * 16 + q * 4];
            const float4 wv = *(const float4*)&w3s[(w * 2 + tc) * 16 + q * 4];
            const float bva[4] = {bv.x, bv.y, bv.z, bv.w};
            const float wva[4] = {wv.x, wv.y, wv.z, wv.w};
            #pragma unroll
            for (int rt = 0; rt < 4; ++rt) {
                ushort4 pk; float dz[4];
                #pragma unroll
                for (int i = 0; i < 4; ++i) {
                    float z = acc[rt][tc][i] + bva[i];
                    if (z > 0.f) { qp[rt] += z * wva[i]; dz[i] = wva[i]; }
                    else         { dz[i] = 0.f; }
                }
                pk.x = f2bf(dz[0]); pk.y = f2bf(dz[1]);
                pk.z = f2bf(dz[2]); pk.w = f2bf(dz[3]);
                *(ushort4*)&B0[(rt * 16 + m) * 264 + (w * 2 + tc) * 16 + q * 4] = pk;
            }
        }
        if (wantq) {
            #pragma unroll
            for (int rt = 0; rt < 4; ++rt) {
                float v = qp[rt];
                v += __shfl_xor(v, 16); v += __shfl_xor(v, 32);
                if (q == 0) qpart[w][rt * 16 + m] = v;
            }
        }
    }
    __syncthreads();                                       // (4)

    if (wantq && tid < RB) {
        float qs = b3[0];
        #pragma unroll
        for (int ww = 0; ww < 8; ++ww) qs += qpart[ww][tid];
        qout[row0 + tid] = qs;
    }

    // ---- Phase D: dh1 = dz2 @ w2^T ; dz1 = dh1 * mask -> B0
    #pragma unroll
    for (int tc = 0; tc < 2; ++tc)
        #pragma unroll
        for (int rt = 0; rt < 4; ++rt) acc[rt][tc] = (f32x4){0.f, 0.f, 0.f, 0.f};
    for (int c = 0; c < 8; ++c) {
        bf16x8 af[4];
        #pragma unroll
        for (int rt = 0; rt < 4; ++rt)
            af[rt] = *(const bf16x8*)&B0[(rt * 16 + m) * 264 + c * 32 + qk];
        #pragma unroll
        for (int tc = 0; tc < 2; ++tc) {
            bf16x8 wfr = *(const bf16x8*)&pB3[(((w * 2 + tc) * 8 + c) * 64 + lane) * 8];
            #pragma unroll
            for (int rt = 0; rt < 4; ++rt)
                acc[rt][tc] = __builtin_amdgcn_mfma_f32_16x16x32_bf16(wfr, af[rt], acc[rt][tc], 0, 0, 0);
        }
    }
    __syncthreads();                                       // (5)
    #pragma unroll
    for (int rt = 0; rt < 4; ++rt)
        #pragma unroll
        for (int tc = 0; tc < 2; ++tc) {
            ushort4 pk;
            pk.x = f2bf((relumask >> (rt * 8 + tc * 4 + 0)) & 1u ? acc[rt][tc][0] : 0.f);
            pk.y = f2bf((relumask >> (rt * 8 + tc * 4 + 1)) & 1u ? acc[rt][tc][1] : 0.f);
            pk.z = f2bf((relumask >> (rt * 8 + tc * 4 + 2)) & 1u ? acc[rt][tc][2] : 0.f);
            pk.w = f2bf((relumask >> (rt * 8 + tc * 4 + 3)) & 1u ? acc[rt][tc][3] : 0.f);
            *(ushort4*)&B0[(rt * 16 + m) * 264 + (w * 2 + tc) * 16 + q * 4] = pk;
        }
    __syncthreads();                                       // (6)

    // ---- Phase E: score = dz1 @ w1[64:80]^T (waves 0..3, row-tile w) -> LDS S
    if (w < 4) {
        f32x4 acc2 = (f32x4){0.f, 0.f, 0.f, 0.f};
        for (int c = 0; c < 8; ++c) {
            bf16x8 af = *(const bf16x8*)&B0[(w * 16 + m) * 264 + c * 32 + qk];
            bf16x8 wfr = *(const bf16x8*)&pB4[(c * 64 + lane) * 8];
            acc2 = __builtin_amdgcn_mfma_f32_16x16x32_bf16(wfr, af, acc2, 0, 0, 0);
        }
        int row = w * 16 + m;
        int st  = row >> 5, sr = row & 31;
        float4 o; o.x = acc2[0]; o.y = acc2[1]; o.z = acc2[2]; o.w = acc2[3];
        *(float4*)&OV[1280 + st * 640 + sr * 20 + q * 4] = o;   // S[st][sr][q*4..]
    }
    __syncthreads();                                       // (7) S visible; B0/B1s free

    // ================= SVGD tail: wave w (0,1) owns state w ==================
    if (w >= 2) return;

    const int stateg  = blockIdx.x * 2 + w;
    const size_t base = (size_t)stateg * 512;      // floats
    float* X  = OV + w * 640;                      // [32][20]
    float* S  = OV + 1280 + w * 640;               // [32][20]
    float* KM = KMOV + w * 1024;                   // [32][32] swizzled

    // ---- stage X = a_in (exact f32), 8 floats/lane
    {
        int g0 = lane * 8;
        int r = g0 >> 4, d0 = g0 & 15;             // d0 in {0,8}
        float4 va0 = *(const float4*)&a_in[base + g0];
        float4 va1 = *(const float4*)&a_in[base + g0 + 4];
        *(float4*)&X[r * 20 + d0]     = va0;
        *(float4*)&X[r * 20 + d0 + 4] = va1;
    }
    __asm__ volatile("s_waitcnt lgkmcnt(0)" ::: "memory");

    const int half = lane >> 5;
    const int j    = lane & 31;

    // ---- dist^2 + P, d0-outer (register-lean; FLOP order == svgd6)
    float ss[16], pp[16];
    #pragma unroll
    for (int t = 0; t < 16; ++t) { ss[t] = 0.f; pp[t] = 0.f; }
    #pragma unroll 1
    for (int d0 = 0; d0 < 16; d0 += 4) {
        float4 xj = *(const float4*)&X[j * 20 + d0];
        float4 sj = *(const float4*)&S[j * 20 + d0];
        #pragma unroll
        for (int t = 0; t < 16; ++t) {
            float4 xi = *(const float4*)&X[(half * 16 + t) * 20 + d0];  // bcast
            float df0 = xi.x - xj.x, df1 = xi.y - xj.y;
            float df2 = xi.z - xj.z, df3 = xi.w - xj.w;
            ss[t] = fmaf(df0, df0, ss[t]); pp[t] = fmaf(df0, sj.x, pp[t]);
            ss[t] = fmaf(df1, df1, ss[t]); pp[t] = fmaf(df1, sj.y, pp[t]);
            ss[t] = fmaf(df2, df2, ss[t]); pp[t] = fmaf(df2, sj.z, pp[t]);
            ss[t] = fmaf(df3, df3, ss[t]); pp[t] = fmaf(df3, sj.w, pp[t]);
        }
    }
    unsigned v[16];
    #pragma unroll
    for (int t = 0; t < 16; ++t) v[t] = __float_as_uint(ss[t]);

    // ---- median via register-only binary rank select (bit-exact)
    {
    }
    unsigned vmin, vmax;
    {
        unsigned mn = 0xFFFFFFFFu, mx = 0u;
        #pragma unroll
        for (int t = 0; t < 16; ++t) {
            mn = min(mn, v[t]); mx = max(mx, v[t]);
        }
        #pragma unroll
        for (int off = 1; off < 64; off <<= 1) {
            mn = min(mn, (unsigned)__shfl_xor((int)mn, off));
            mx = max(mx, (unsigned)__shfl_xor((int)mx, off));
        }
        vmin = mn; vmax = mx;
    }
    unsigned lo = vmin, hi = vmax;
    while (lo < hi) {                       // uniform across the wave
        unsigned mid = lo + ((hi - lo) >> 1);
        int c = 0;
        #pragma unroll
        for (int t = 0; t < 16; ++t) c += (v[t] <= mid) ? 1 : 0;
        #pragma unroll
        for (int off = 1; off < 64; off <<= 1) c += __shfl_xor(c, off);
        if (c >= 512) hi = mid; else lo = mid + 1;
    }
    const unsigned prefix = lo;             // bits of sorted[511]
    const float v1 = __uint_as_float(prefix);

    // ---- rank-512: v1 if count(x<=v1)>=513 else min of x>v1 (wave reduce)
    int cle = 0;
    unsigned mgt = 0xFFFFFFFFu;
    #pragma unroll
    for (int t = 0; t < 16; ++t) {
        if (v[t] <= prefix) cle++;
        else mgt = min(mgt, v[t]);
    }
    #pragma unroll
    for (int off = 1; off < 64; off <<= 1) {
        cle += __shfl_xor(cle, off);
        mgt = min(mgt, (unsigned)__shfl_xor((int)mgt, off));
    }
    const float v2  = (cle >= 513) ? v1 : __uint_as_float(mgt);
    const float med = 0.5f * (v1 + v2);
    const float gamma = 1.0f / (2.0f * (med / LN32 + 1e-8f));

    // ---- K -> swizzled KM ; logp row-reduce fused in
    #pragma unroll 4
    for (int t = 0; t < 16; ++t) {
        int i = half * 16 + t;
        float kk = __expf(-gamma * __uint_as_float(v[t]));
        KM[i * 32 + (j ^ i)] = kk;
        float acc2 = fmaf(fmaf(2.f * gamma, __uint_as_float(v[t]), -16.f), kk,
                          kk * pp[t]);
        #pragma unroll
        for (int off = 1; off < 32; off <<= 1)
            acc2 += __shfl_xor(acc2, off);
        if (j == 0) {
            float tmp = -2.f * gamma * acc2 * (1.f / 32.f);
            float prev = first ? 0.f : logp_in[stateg * 32 + i];
            logp_out[stateg * 32 + i] = prev - 0.1f * tmp;
        }
    }
    __asm__ volatile("s_waitcnt lgkmcnt(0)" ::: "memory");

    // ---- phi + particle update: lane owns 8 (i,d) entries, d = lane&15
    {
        const int d  = lane & 15;
        const int i0 = lane >> 4;              // entry e -> row i0 + 4e
        float s1[8], s2[8], xi[8];
        #pragma unroll
        for (int e = 0; e < 8; ++e) {
            s1[e] = 0.f; s2[e] = 0.f;
            xi[e] = X[(i0 + 4 * e) * 20 + d];
        }
        for (int jj = 0; jj < 32; ++jj) {
            float xjv = X[jj * 20 + d];
            float sjv = S[jj * 20 + d];
            #pragma unroll
            for (int e = 0; e < 8; ++e) {
                int i = i0 + 4 * e;
                float kk = KM[i * 32 + (jj ^ i)];
                s1[e] = fmaf(kk, sjv, s1[e]);
                s2[e] = fmaf(kk, xi[e] - xjv, s2[e]);
            }
        }
        #pragma unroll
        for (int e = 0; e < 8; ++e) {
            int i = i0 + 4 * e;
            float phi = (s1[e] + 2.f * gamma * s2[e]) * (1.f / 32.f);
            float av = xi[e] + 0.1f * phi;
            av = fminf(fmaxf(av, -1.f), 1.f);
            a_out[base + i * 16 + d] = av;
        }
    }
}

// ---------------------------------------------------------------------------
extern "C" void kernel_launch(void* const* d_in, const int* in_sizes, int n_in,
                              void* d_out, int out_size, void* d_ws, size_t ws_size,
                              hipStream_t stream) {
    const float* obs = (const float*)d_in[0];
    const float* a0  = (const float*)d_in[1];
    const float* w1  = (const float*)d_in[2];
    const float* b1  = (const float*)d_in[3];
    const float* w2  = (const float*)d_in[4];
    const float* b2  = (const float*)d_in[5];
    const float* w3  = (const float*)d_in[6];
    const float* b3  = (const float*)d_in[7];

    float* out_a    = (float*)d_out;                 // [BN,16]
    float* out_logp = out_a + (size_t)BNROWS * 16;   // [BN]
    float* out_q    = out_logp + BNROWS;             // [BN]

    char* p = (char*)d_ws;
    ushort* pB1 = (ushort*)p; p += 24576 * 2;
    ushort* pB2 = (ushort*)p; p += 65536 * 2;
    ushort* pB3 = (ushort*)p; p += 65536 * 2;
    ushort* pB4 = (ushort*)p; p += 4096 * 2;
    float* abuf0 = (float*)p; p += (size_t)BNROWS * 16 * 4;
    float* abuf1 = (float*)p; p += (size_t)BNROWS * 16 * 4;
    float* logp  = (float*)p; p += (size_t)BNROWS * 4;
    float* qtmp  = (float*)p;

    prep_pack<<<78, 256, 0, stream>>>(w1, w2, pB1, pB2, pB3, pB4);

    const int MB = BNROWS / RB;   // 2048 blocks, 2 states each

    // step 1
    fused_step<<<MB, 512, 0, stream>>>(obs, a0, b1, b2, w3, b3,
                                       pB1, pB2, pB3, pB4,
                                       nullptr, logp, abuf0, qtmp, 1, 0);
    // step 2
    fused_step<<<MB, 512, 0, stream>>>(obs, abuf0, b1, b2, w3, b3,
                                       pB1, pB2, pB3, pB4,
                                       logp, logp, abuf1, qtmp, 0, 0);
    // step 3 (q of this step is the q_vals output)
    fused_step<<<MB, 512, 0, stream>>>(obs, abuf1, b1, b2, w3, b3,
                                       pB1, pB2, pB3, pB4,
                                       logp, out_logp, out_a, out_q, 0, 1);
}

// Round 12
// 311.601 us; speedup vs baseline: 1.5241x; 1.5241x over previous
//
#include <hip/hip_runtime.h>
#include <hip/hip_bf16.h>
#include <math.h>

#define BNROWS (4096*32)   // 131072
#define RB     64          // rows per MLP block
#define LN32   3.4657359027997265f

typedef __attribute__((ext_vector_type(8))) short bf16x8;
typedef __attribute__((ext_vector_type(4))) float f32x4;

static __device__ __forceinline__ ushort f2bf(float x) {
    union { __hip_bfloat16 h; ushort u; } cv;
    cv.h = __float2bfloat16(x);
    return cv.u;
}

// ---------------------------------------------------------------------------
// Weight pack (fragment order for lane-contiguous 16B loads).
__global__ void prep_pack(const float* __restrict__ w1,
                          const float* __restrict__ w2,
                          ushort* __restrict__ pB1, ushort* __restrict__ pB2,
                          ushort* __restrict__ pB3, ushort* __restrict__ pB4) {
    int g = blockIdx.x * 256 + threadIdx.x;   // 19968 total
    ushort out[8];
    ushort* dst;
    if (g < 3072) {
        int lane = g & 63, gc = g >> 6;
        int t = gc / 3, c = gc % 3;
        int m = lane & 15, q = lane >> 4, n = t * 16 + m;
        #pragma unroll
        for (int j = 0; j < 8; ++j) {
            int k = c * 32 + q * 8 + j;
            out[j] = f2bf((k < 80) ? w1[k * 256 + n] : 0.f);
        }
        dst = &pB1[g * 8];
    } else if (g < 11264) {
        int gg = g - 3072;
        int lane = gg & 63, gc = gg >> 6;
        int t = gc >> 3, c = gc & 7;
        int m = lane & 15, q = lane >> 4, n = t * 16 + m;
        #pragma unroll
        for (int j = 0; j < 8; ++j)
            out[j] = f2bf(w2[(c * 32 + q * 8 + j) * 256 + n]);
        dst = &pB2[gg * 8];
    } else if (g < 19456) {
        int gg = g - 11264;
        int lane = gg & 63, gc = gg >> 6;
        int t = gc >> 3, c = gc & 7;
        int m = lane & 15, q = lane >> 4;
        #pragma unroll
        for (int j = 0; j < 8; ++j)
            out[j] = f2bf(w2[(t * 16 + m) * 256 + c * 32 + q * 8 + j]);
        dst = &pB3[gg * 8];
    } else if (g < 19968) {
        int gg = g - 19456;
        int lane = gg & 63, c = gg >> 6;
        int m = lane & 15, q = lane >> 4;
        #pragma unroll
        for (int j = 0; j < 8; ++j)
            out[j] = f2bf(w1[(64 + m) * 256 + c * 32 + q * 8 + j]);
        dst = &pB4[gg * 8];
    } else return;
    *(uint4*)dst = *(uint4*)out;
}

// ---------------------------------------------------------------------------
// Fused critic forward + VJP, bf16 MFMA — round-6 structure (proven), with
// obs staged straight from f32 global in phase A (round-10, proven).
// Round-11 lesson: tail-fusing svgd regressed (147.9 us) — early-exiting
// waves don't free block resources; tails of lockstep blocks coincide.
__global__ __launch_bounds__(512) void mlp_mfma(
    const float* __restrict__ obs,      // [BN,64] f32
    const float* __restrict__ a_in,     // [BN,16]
    const float* __restrict__ b1,       // [256]
    const float* __restrict__ b2,       // [256]
    const float* __restrict__ w3,       // [256]
    const float* __restrict__ b3,       // [1]
    const ushort* __restrict__ pB1, const ushort* __restrict__ pB2,
    const ushort* __restrict__ pB3, const ushort* __restrict__ pB4,
    float* __restrict__ score,          // [BN,16]
    float* __restrict__ qout,           // [BN]
    int wantq)
{
    __shared__ __align__(16) ushort B0[RB * 264];   // h1 -> dz2 -> dz1
    __shared__ __align__(16) ushort B1s[RB * 104];  // h0
    __shared__ float qpart[8][RB];
    __shared__ float bias1[256], bias2[256], w3s[256];

    const int tid  = threadIdx.x;
    const int row0 = blockIdx.x * RB;

    // ---- Phase A: stage h0 = [obs(f32->bf16) | a->bf16 | 0pad] at stride 104
    {
        int r = tid >> 3, ch = tid & 7;                    // 512 units exactly
        const float* op = &obs[(size_t)(row0 + r) * 64 + ch * 8];
        float4 v0 = *(const float4*)op;
        float4 v1 = *(const float4*)(op + 4);
        ushort o[8];
        o[0] = f2bf(v0.x); o[1] = f2bf(v0.y); o[2] = f2bf(v0.z); o[3] = f2bf(v0.w);
        o[4] = f2bf(v1.x); o[5] = f2bf(v1.y); o[6] = f2bf(v1.z); o[7] = f2bf(v1.w);
        *(uint4*)&B1s[r * 104 + ch * 8] = *(uint4*)o;
    }
    if (tid < 256) {
        int r = tid >> 2, d0 = (tid & 3) * 4;
        float4 av = *(const float4*)&a_in[(size_t)(row0 + r) * 16 + d0];
        ushort4 pv;
        pv.x = f2bf(av.x); pv.y = f2bf(av.y); pv.z = f2bf(av.z); pv.w = f2bf(av.w);
        *(ushort4*)&B1s[r * 104 + 64 + d0] = pv;
        ushort4 zv; zv.x = zv.y = zv.z = zv.w = 0;
        *(ushort4*)&B1s[r * 104 + 80 + d0] = zv;
        bias1[tid] = b1[tid]; bias2[tid] = b2[tid]; w3s[tid] = w3[tid];
    }
    __syncthreads();                                       // (1)

    const int lane = tid & 63;
    const int w    = tid >> 6;        // wave 0..7 -> col-tiles {2w, 2w+1}
    const int m    = lane & 15;
    const int q    = lane >> 4;
    const int qk   = q * 8;

    f32x4 acc[4][2];                  // [row-tile][col-tile-in-wave]
    unsigned relumask = 0u;           // 32 bits: rt*8 + tc*4 + i

    // ---- Phase B: z1 = h0 @ w1 (+b1) ; relu -> B0 ; mask -> regs
    #pragma unroll
    for (int tc = 0; tc < 2; ++tc)
        #pragma unroll
        for (int rt = 0; rt < 4; ++rt) acc[rt][tc] = (f32x4){0.f, 0.f, 0.f, 0.f};
    for (int c = 0; c < 3; ++c) {
        bf16x8 af[4];
        #pragma unroll
        for (int rt = 0; rt < 4; ++rt)
            af[rt] = *(const bf16x8*)&B1s[(rt * 16 + m) * 104 + c * 32 + qk];
        #pragma unroll
        for (int tc = 0; tc < 2; ++tc) {
            bf16x8 wfr = *(const bf16x8*)&pB1[(((w * 2 + tc) * 3 + c) * 64 + lane) * 8];
            #pragma unroll
            for (int rt = 0; rt < 4; ++rt)
                acc[rt][tc] = __builtin_amdgcn_mfma_f32_16x16x32_bf16(wfr, af[rt], acc[rt][tc], 0, 0, 0);
        }
    }
    #pragma unroll
    for (int tc = 0; tc < 2; ++tc) {
        const float4 bv = *(const float4*)&bias1[(w * 2 + tc) * 16 + q * 4];
        const float bva[4] = {bv.x, bv.y, bv.z, bv.w};
        #pragma unroll
        for (int rt = 0; rt < 4; ++rt) {
            ushort4 pk;
            float z0 = acc[rt][tc][0] + bva[0];
            float z1 = acc[rt][tc][1] + bva[1];
            float z2 = acc[rt][tc][2] + bva[2];
            float z3 = acc[rt][tc][3] + bva[3];
            if (z0 > 0.f) relumask |= 1u << (rt * 8 + tc * 4 + 0);
            if (z1 > 0.f) relumask |= 1u << (rt * 8 + tc * 4 + 1);
            if (z2 > 0.f) relumask |= 1u << (rt * 8 + tc * 4 + 2);
            if (z3 > 0.f) relumask |= 1u << (rt * 8 + tc * 4 + 3);
            pk.x = f2bf(fmaxf(z0, 0.f)); pk.y = f2bf(fmaxf(z1, 0.f));
            pk.z = f2bf(fmaxf(z2, 0.f)); pk.w = f2bf(fmaxf(z3, 0.f));
            *(ushort4*)&B0[(rt * 16 + m) * 264 + (w * 2 + tc) * 16 + q * 4] = pk;
        }
    }
    __syncthreads();                                       // (2)

    // ---- Phase C: z2 = h1 @ w2 (+b2) ; q partials (wantq) ; dz2 -> B0
    #pragma unroll
    for (int tc = 0; tc < 2; ++tc)
        #pragma unroll
        for (int rt = 0; rt < 4; ++rt) acc[rt][tc] = (f32x4){0.f, 0.f, 0.f, 0.f};
    for (int c = 0; c < 8; ++c) {
        bf16x8 af[4];
        #pragma unroll
        for (int rt = 0; rt < 4; ++rt)
            af[rt] = *(const bf16x8*)&B0[(rt * 16 + m) * 264 + c * 32 + qk];
        #pragma unroll
        for (int tc = 0; tc < 2; ++tc) {
            bf16x8 wfr = *(const bf16x8*)&pB2[(((w * 2 + tc) * 8 + c) * 64 + lane) * 8];
            #pragma unroll
            for (int rt = 0; rt < 4; ++rt)
                acc[rt][tc] = __builtin_amdgcn_mfma_f32_16x16x32_bf16(wfr, af[rt], acc[rt][tc], 0, 0, 0);
        }
    }
    __syncthreads();                                       // (3)
    {
        float qp[4] = {0.f, 0.f, 0.f, 0.f};
        #pragma unroll
        for (int tc = 0; tc < 2; ++tc) {
            const float4 bv = *(const float4*)&bias2[(w * 2 + tc) * 16 + q * 4];
            const float4 wv = *(const float4*)&w3s[(w * 2 + tc) * 16 + q * 4];
            const float bva[4] = {bv.x, bv.y, bv.z, bv.w};
            const float wva[4] = {wv.x, wv.y, wv.z, wv.w};
            #pragma unroll
            for (int rt = 0; rt < 4; ++rt) {
                ushort4 pk; float dz[4];
                #pragma unroll
                for (int i = 0; i < 4; ++i) {
                    float z = acc[rt][tc][i] + bva[i];
                    if (z > 0.f) { qp[rt] += z * wva[i]; dz[i] = wva[i]; }
                    else         { dz[i] = 0.f; }
                }
                pk.x = f2bf(dz[0]); pk.y = f2bf(dz[1]);
                pk.z = f2bf(dz[2]); pk.w = f2bf(dz[3]);
                *(ushort4*)&B0[(rt * 16 + m) * 264 + (w * 2 + tc) * 16 + q * 4] = pk;
            }
        }
        if (wantq) {
            #pragma unroll
            for (int rt = 0; rt < 4; ++rt) {
                float v = qp[rt];
                v += __shfl_xor(v, 16); v += __shfl_xor(v, 32);
                if (q == 0) qpart[w][rt * 16 + m] = v;
            }
        }
    }
    __syncthreads();                                       // (4)

    if (wantq && tid < RB) {
        float qs = b3[0];
        #pragma unroll
        for (int ww = 0; ww < 8; ++ww) qs += qpart[ww][tid];
        qout[row0 + tid] = qs;
    }

    // ---- Phase D: dh1 = dz2 @ w2^T ; dz1 = dh1 * mask -> B0
    #pragma unroll
    for (int tc = 0; tc < 2; ++tc)
        #pragma unroll
        for (int rt = 0; rt < 4; ++rt) acc[rt][tc] = (f32x4){0.f, 0.f, 0.f, 0.f};
    for (int c = 0; c < 8; ++c) {
        bf16x8 af[4];
        #pragma unroll
        for (int rt = 0; rt < 4; ++rt)
            af[rt] = *(const bf16x8*)&B0[(rt * 16 + m) * 264 + c * 32 + qk];
        #pragma unroll
        for (int tc = 0; tc < 2; ++tc) {
            bf16x8 wfr = *(const bf16x8*)&pB3[(((w * 2 + tc) * 8 + c) * 64 + lane) * 8];
            #pragma unroll
            for (int rt = 0; rt < 4; ++rt)
                acc[rt][tc] = __builtin_amdgcn_mfma_f32_16x16x32_bf16(wfr, af[rt], acc[rt][tc], 0, 0, 0);
        }
    }
    __syncthreads();                                       // (5)
    #pragma unroll
    for (int rt = 0; rt < 4; ++rt)
        #pragma unroll
        for (int tc = 0; tc < 2; ++tc) {
            ushort4 pk;
            pk.x = f2bf((relumask >> (rt * 8 + tc * 4 + 0)) & 1u ? acc[rt][tc][0] : 0.f);
            pk.y = f2bf((relumask >> (rt * 8 + tc * 4 + 1)) & 1u ? acc[rt][tc][1] : 0.f);
            pk.z = f2bf((relumask >> (rt * 8 + tc * 4 + 2)) & 1u ? acc[rt][tc][2] : 0.f);
            pk.w = f2bf((relumask >> (rt * 8 + tc * 4 + 3)) & 1u ? acc[rt][tc][3] : 0.f);
            *(ushort4*)&B0[(rt * 16 + m) * 264 + (w * 2 + tc) * 16 + q * 4] = pk;
        }
    __syncthreads();                                       // (6)

    // ---- Phase E: score = dz1 @ w1[64:80]^T (waves 0..3, row-tile w)
    if (w < 4) {
        f32x4 acc2 = (f32x4){0.f, 0.f, 0.f, 0.f};
        for (int c = 0; c < 8; ++c) {
            bf16x8 af = *(const bf16x8*)&B0[(w * 16 + m) * 264 + c * 32 + qk];
            bf16x8 wfr = *(const bf16x8*)&pB4[(c * 64 + lane) * 8];
            acc2 = __builtin_amdgcn_mfma_f32_16x16x32_bf16(wfr, af, acc2, 0, 0, 0);
        }
        float4 o; o.x = acc2[0]; o.y = acc2[1]; o.z = acc2[2]; o.w = acc2[3];
        *(float4*)&score[(size_t)(row0 + w * 16 + m) * 16 + q * 4] = o;
    }
}

// ---------------------------------------------------------------------------
// SVGD v6.3 (round 12): round-6 proven structure; the rank-select count
// reduces switched from 6-deep shfl_xor chains (~210 cy cross-lane latency
// per iteration, ~25 dependent iterations) to BALLOT+POPCOUNT:
//   c += __popcll(__ballot(v[t] <= mid))
// compiles to v_cmp -> sgpr mask -> s_bcnt1_b64: the reduction happens on
// the scalar pipe with zero cross-lane data movement, and the 16 ballots
// pipeline. Count is bit-identical -> med/gamma/outputs unchanged. Same
// trick for cle; mgt (a value min, run once) keeps its shfl reduce.
__global__ __launch_bounds__(256, 2) void svgd6(
    const float* __restrict__ a_in,    // [BN,16]
    const float* __restrict__ score,   // [BN,16]
    const float* __restrict__ logp_in, // [BN] (ignored if first)
    float* __restrict__ logp_out,      // [BN]
    float* __restrict__ a_out,         // [BN,16]
    int first)
{
    __shared__ __align__(16) float X4[4][32 * 20];
    __shared__ __align__(16) float S4[4][32 * 20];
    __shared__ __align__(16) float KM4[4][1024];

    const int tid    = threadIdx.x;
    const int wv     = tid >> 6;
    const int lane   = tid & 63;
    const int stateg = blockIdx.x * 4 + wv;
    const size_t base = (size_t)stateg * 512;      // floats

    float* X  = X4[wv];
    float* S  = S4[wv];
    float* KM = KM4[wv];

    // ---- stage own state's a/score (wave-local; 8 floats per lane per array)
    {
        int g0 = lane * 8;
        int r = g0 >> 4, d0 = g0 & 15;             // d0 in {0,8}
        float4 va0 = *(const float4*)&a_in[base + g0];
        float4 va1 = *(const float4*)&a_in[base + g0 + 4];
        float4 vs0 = *(const float4*)&score[base + g0];
        float4 vs1 = *(const float4*)&score[base + g0 + 4];
        *(float4*)&X[r * 20 + d0]     = va0;
        *(float4*)&X[r * 20 + d0 + 4] = va1;
        *(float4*)&S[r * 20 + d0]     = vs0;
        *(float4*)&S[r * 20 + d0 + 4] = vs1;
    }
    __asm__ volatile("s_waitcnt lgkmcnt(0)" ::: "memory");

    const int half = lane >> 5;
    const int j    = lane & 31;

    // ---- cache own column (rows X[j], S[j]) in registers
    float Xj[16], Sj[16];
    #pragma unroll
    for (int d0 = 0; d0 < 16; d0 += 4) {
        float4 xv = *(const float4*)&X[j * 20 + d0];
        float4 sv = *(const float4*)&S[j * 20 + d0];
        Xj[d0 + 0] = xv.x; Xj[d0 + 1] = xv.y; Xj[d0 + 2] = xv.z; Xj[d0 + 3] = xv.w;
        Sj[d0 + 0] = sv.x; Sj[d0 + 1] = sv.y; Sj[d0 + 2] = sv.z; Sj[d0 + 3] = sv.w;
    }

    // ---- dist^2 (as uint bits) + P for 16 pairs (i = half*16+t, j)
    unsigned v[16]; float p[16];
    #pragma unroll 4
    for (int t = 0; t < 16; ++t) {
        const float* Xi = &X[(half * 16 + t) * 20];
        float ss = 0.f, pp = 0.f;
        #pragma unroll
        for (int d0 = 0; d0 < 16; d0 += 4) {
            float4 xv = *(const float4*)&Xi[d0];
            float df0 = xv.x - Xj[d0 + 0];
            float df1 = xv.y - Xj[d0 + 1];
            float df2 = xv.z - Xj[d0 + 2];
            float df3 = xv.w - Xj[d0 + 3];
            ss = fmaf(df0, df0, ss); pp = fmaf(df0, Sj[d0 + 0], pp);
            ss = fmaf(df1, df1, ss); pp = fmaf(df1, Sj[d0 + 1], pp);
            ss = fmaf(df2, df2, ss); pp = fmaf(df2, Sj[d0 + 2], pp);
            ss = fmaf(df3, df3, ss); pp = fmaf(df3, Sj[d0 + 3], pp);
        }
        v[t] = __float_as_uint(ss);
        p[t] = pp;
    }

    // ---- median via register-only binary rank select (bit-exact).
    // Counts via ballot+popcount (scalar-pipe reduce, no shfl chains).
    unsigned vmin, vmax;
    {
        unsigned mn = 0xFFFFFFFFu, mx = 0u;
        #pragma unroll
        for (int t = 0; t < 16; ++t) {
            mn = min(mn, v[t]); mx = max(mx, v[t]);
        }
        #pragma unroll
        for (int off = 1; off < 64; off <<= 1) {
            mn = min(mn, (unsigned)__shfl_xor((int)mn, off));
            mx = max(mx, (unsigned)__shfl_xor((int)mx, off));
        }
        vmin = mn; vmax = mx;
    }
    unsigned lo = vmin, hi = vmax;
    while (lo < hi) {                       // uniform across the wave
        unsigned mid = lo + ((hi - lo) >> 1);
        int c = 0;
        #pragma unroll
        for (int t = 0; t < 16; ++t)
            c += (int)__popcll(__ballot(v[t] <= mid));
        if (c >= 512) hi = mid; else lo = mid + 1;
    }
    const unsigned prefix = lo;             // bits of sorted[511]
    const float v1 = __uint_as_float(prefix);

    // ---- rank-512: v1 if count(x<=v1)>=513 else min of x>v1
    int cle = 0;
    {
        #pragma unroll
        for (int t = 0; t < 16; ++t)
            cle += (int)__popcll(__ballot(v[t] <= prefix));
    }
    unsigned mgt = 0xFFFFFFFFu;
    #pragma unroll
    for (int t = 0; t < 16; ++t)
        if (v[t] > prefix) mgt = min(mgt, v[t]);
    #pragma unroll
    for (int off = 1; off < 64; off <<= 1)
        mgt = min(mgt, (unsigned)__shfl_xor((int)mgt, off));
    const float v2  = (cle >= 513) ? v1 : __uint_as_float(mgt);
    const float med = 0.5f * (v1 + v2);
    const float gamma = 1.0f / (2.0f * (med / LN32 + 1e-8f));

    // ---- K -> swizzled KM ; logp row-reduce fused in
    #pragma unroll 4
    for (int t = 0; t < 16; ++t) {
        int i = half * 16 + t;
        float kk = __expf(-gamma * __uint_as_float(v[t]));
        KM[i * 32 + (j ^ i)] = kk;
        float acc = fmaf(fmaf(2.f * gamma, __uint_as_float(v[t]), -16.f), kk,
                         kk * p[t]);
        #pragma unroll
        for (int off = 1; off < 32; off <<= 1)
            acc += __shfl_xor(acc, off);
        if (j == 0) {
            float tmp = -2.f * gamma * acc * (1.f / 32.f);
            float prev = first ? 0.f : logp_in[stateg * 32 + i];
            logp_out[stateg * 32 + i] = prev - 0.1f * tmp;
        }
    }
    __asm__ volatile("s_waitcnt lgkmcnt(0)" ::: "memory");

    // ---- phi + particle update: lane owns 8 (i,d) entries, d = lane&15
    {
        const int d  = lane & 15;
        const int i0 = lane >> 4;              // entry e -> row i0 + 4e
        float s1[8], s2[8], xi[8];
        #pragma unroll
        for (int e = 0; e < 8; ++e) {
            s1[e] = 0.f; s2[e] = 0.f;
            xi[e] = X[(i0 + 4 * e) * 20 + d];
        }
        for (int jj = 0; jj < 32; ++jj) {
            float xjv = X[jj * 20 + d];
            float sjv = S[jj * 20 + d];
            #pragma unroll
            for (int e = 0; e < 8; ++e) {
                int i = i0 + 4 * e;
                float kk = KM[i * 32 + (jj ^ i)];
                s1[e] = fmaf(kk, sjv, s1[e]);
                s2[e] = fmaf(kk, xi[e] - xjv, s2[e]);
            }
        }
        #pragma unroll
        for (int e = 0; e < 8; ++e) {
            int i = i0 + 4 * e;
            float phi = (s1[e] + 2.f * gamma * s2[e]) * (1.f / 32.f);
            float av = xi[e] + 0.1f * phi;
            av = fminf(fmaxf(av, -1.f), 1.f);
            a_out[base + i * 16 + d] = av;
        }
    }
}

// ---------------------------------------------------------------------------
extern "C" void kernel_launch(void* const* d_in, const int* in_sizes, int n_in,
                              void* d_out, int out_size, void* d_ws, size_t ws_size,
                              hipStream_t stream) {
    const float* obs = (const float*)d_in[0];
    const float* a0  = (const float*)d_in[1];
    const float* w1  = (const float*)d_in[2];
    const float* b1  = (const float*)d_in[3];
    const float* w2  = (const float*)d_in[4];
    const float* b2  = (const float*)d_in[5];
    const float* w3  = (const float*)d_in[6];
    const float* b3  = (const float*)d_in[7];

    float* out_a    = (float*)d_out;                 // [BN,16]
    float* out_logp = out_a + (size_t)BNROWS * 16;   // [BN]
    float* out_q    = out_logp + BNROWS;             // [BN]

    char* p = (char*)d_ws;
    ushort* pB1 = (ushort*)p; p += 24576 * 2;
    ushort* pB2 = (ushort*)p; p += 65536 * 2;
    ushort* pB3 = (ushort*)p; p += 65536 * 2;
    ushort* pB4 = (ushort*)p; p += 4096 * 2;
    float* abuf0 = (float*)p; p += (size_t)BNROWS * 16 * 4;
    float* abuf1 = (float*)p; p += (size_t)BNROWS * 16 * 4;
    float* scr   = (float*)p; p += (size_t)BNROWS * 16 * 4;
    float* logp  = (float*)p; p += (size_t)BNROWS * 4;
    float* qtmp  = (float*)p;

    prep_pack<<<78, 256, 0, stream>>>(w1, w2, pB1, pB2, pB3, pB4);

    const int MB = BNROWS / RB;   // 2048 blocks
    const int SB = 4096 / 4;      // 1024 blocks, 4 states (waves) each

    // step 1
    mlp_mfma<<<MB, 512, 0, stream>>>(obs, a0, b1, b2, w3, b3,
                                     pB1, pB2, pB3, pB4, scr, qtmp, 0);
    svgd6<<<SB, 256, 0, stream>>>(a0, scr, nullptr, logp, abuf0, 1);
    // step 2
    mlp_mfma<<<MB, 512, 0, stream>>>(obs, abuf0, b1, b2, w3, b3,
                                     pB1, pB2, pB3, pB4, scr, qtmp, 0);
    svgd6<<<SB, 256, 0, stream>>>(abuf0, scr, logp, logp, abuf1, 0);
    // step 3 (q of this step is the q_vals output)
    mlp_mfma<<<MB, 512, 0, stream>>>(obs, abuf1, b1, b2, w3, b3,
                                     pB1, pB2, pB3, pB4, scr, out_q, 1);
    svgd6<<<SB, 256, 0, stream>>>(abuf1, scr, logp, out_logp, out_a, 0);
}